// Round 5
// baseline (397.513 us; speedup 1.0000x reference)
//
#include <hip/hip_runtime.h>
#include <hip/hip_bf16.h>
#include <stdint.h>

// ---------------------------------------------------------------------------
// OneEventExtracter: proj GEMM (f32 in -> bf16 MFMA) + RoPE + 62-head QK^T.
// B=16, L=256, H=1024, heads: [tri, arg, role0..59], head_dim=64.
// Inputs f32, OUTPUTS FLOAT32 (d_out is float*; 65,011,712 f32 elems).
// Masked slots store exact bf16-cast constant -1000727379968.0f (ref is
// bf16-cast np, so masked err == 0). Scratch q/k kept as bf16.
// ---------------------------------------------------------------------------

typedef __attribute__((ext_vector_type(8)))  short short8;
typedef __attribute__((ext_vector_type(4)))  float f32x4;

#define LQ    256
#define HID   1024
#define QKS   3968                 // 62 heads * 64
#define NEGF  (-1000727379968.0f)  // bf16(-1e12) as f32 — matches bf16-cast ref
#define TA_OFF   1048576ULL        // arg output offset (f32 elems)
#define ROLE_OFF 2097152ULL        // role output offset (f32 elems)

__device__ __forceinline__ uint16_t f2bf(float x) {          // RNE
  uint32_t u = __builtin_bit_cast(uint32_t, x);
  return (uint16_t)((u + 0x7FFFu + ((u >> 16) & 1u)) >> 16);
}
__device__ __forceinline__ uint16_t f2bf_tr(float x) {       // truncate (GEMM in)
  return (uint16_t)(__builtin_bit_cast(uint32_t, x) >> 16);
}
__device__ __forceinline__ float bf2f(uint16_t b) {
  uint32_t u = ((uint32_t)b) << 16;
  return __builtin_bit_cast(float, u);
}
__device__ __forceinline__ int mask_mode(const void* p) {
  uint32_t w0 = *(const uint32_t*)p;
  if (w0 == 0x01010101u) return 0;   // bool bytes
  if (w0 == 1u)          return 1;   // int32
  if (w0 == 0x3F803F80u) return 2;   // bf16
  return 3;                          // f32
}
__device__ __forceinline__ bool mask_at(const void* p, int mode, size_t idx) {
  if (mode == 0) return ((const uint8_t*)p)[idx] != 0;
  if (mode == 1) return ((const int*)p)[idx] != 0;
  if (mode == 2) return (((const uint16_t*)p)[idx] & 0x7FFFu) != 0;
  return ((const float*)p)[idx] != 0.0f;
}
// RoPE angle: pos * 10000^(-p/32), p = d>>1
__device__ __forceinline__ void rope_cs(int pos, float invf, float* s, float* c) {
  float ang = (float)pos * invf;
  __sincosf(ang, s, c);
}
__device__ __forceinline__ float rope_invf(int p) {
  return exp2f(-(float)p * (13.287712379549449f / 32.0f));
}

// ---------------------------------------------------------------------------
// Projection GEMM chunk: rows [b0*256, b0*256 + cb*256) of C = E·W^T (+bias),
// RoPE, split q/k to bf16 scratch (chunk-local rows). 128x128 tile, BK=32.
// grid: (62 n-tiles, 2*cb m-tiles)
// ---------------------------------------------------------------------------
__global__ __launch_bounds__(256)
void k_proj_chunk(const float* __restrict__ E,
                  const float* __restrict__ triW, const float* __restrict__ triB,
                  const float* __restrict__ argW, const float* __restrict__ argB,
                  const float* __restrict__ roleW, const float* __restrict__ roleB,
                  short* __restrict__ qs, short* __restrict__ ks, int b0) {
  const int nb = blockIdx.x;          // 0..61
  const int mb = blockIdx.y;          // chunk-local 128-row tile
  const int n0 = nb * 128;
  const int mrow0 = b0 * LQ + mb * 128;   // global E row base
  const int lrow0 = mb * 128;             // chunk-local scratch row base

  const float* W;  const float* Bv;
  if (nb == 0)      { W = triW;                             Bv = triB; }
  else if (nb == 1) { W = argW;                             Bv = argB; }
  else              { W = roleW + (size_t)(n0 - 256) * HID; Bv = roleB + (n0 - 256); }

  __shared__ short As[2][128 * 32];
  __shared__ short Bs[2][128 * 32];

  const int tid  = threadIdx.x;
  const int lane = tid & 63;
  const int w    = tid >> 6;
  const int wm   = (w >> 1) * 64, wn = (w & 1) * 64;
  const int srow = tid >> 2;          // 0..63 (rows srow, srow+64)
  const int scol = (tid & 3) * 8;     // k offset 0/8/16/24

  f32x4 acc[4][4] = {};
  f32x4 ra0[2], ra1[2], rb0[2], rb1[2];

  auto load_regs = [&](int k0) {
    const float* pa0 = E + (size_t)(mrow0 + srow) * HID + k0 + scol;
    const float* pa1 = E + (size_t)(mrow0 + 64 + srow) * HID + k0 + scol;
    const float* pb0 = W + (size_t)(srow) * HID + k0 + scol;
    const float* pb1 = W + (size_t)(64 + srow) * HID + k0 + scol;
    ra0[0] = *reinterpret_cast<const f32x4*>(pa0);
    ra0[1] = *reinterpret_cast<const f32x4*>(pa0 + 4);
    ra1[0] = *reinterpret_cast<const f32x4*>(pa1);
    ra1[1] = *reinterpret_cast<const f32x4*>(pa1 + 4);
    rb0[0] = *reinterpret_cast<const f32x4*>(pb0);
    rb0[1] = *reinterpret_cast<const f32x4*>(pb0 + 4);
    rb1[0] = *reinterpret_cast<const f32x4*>(pb1);
    rb1[1] = *reinterpret_cast<const f32x4*>(pb1 + 4);
  };
  auto cvt8 = [&](const f32x4* v) -> short8 {
    short8 r;
    r[0] = (short)f2bf_tr(v[0][0]); r[1] = (short)f2bf_tr(v[0][1]);
    r[2] = (short)f2bf_tr(v[0][2]); r[3] = (short)f2bf_tr(v[0][3]);
    r[4] = (short)f2bf_tr(v[1][0]); r[5] = (short)f2bf_tr(v[1][1]);
    r[6] = (short)f2bf_tr(v[1][2]); r[7] = (short)f2bf_tr(v[1][3]);
    return r;
  };
  auto write_lds = [&](int buf) {
    *reinterpret_cast<short8*>(&As[buf][srow * 32 + scol])        = cvt8(ra0);
    *reinterpret_cast<short8*>(&As[buf][(64 + srow) * 32 + scol]) = cvt8(ra1);
    *reinterpret_cast<short8*>(&Bs[buf][srow * 32 + scol])        = cvt8(rb0);
    *reinterpret_cast<short8*>(&Bs[buf][(64 + srow) * 32 + scol]) = cvt8(rb1);
  };

  load_regs(0); write_lds(0); __syncthreads();
  const int NT = HID / 32;
  for (int t = 0; t < NT; ++t) {
    if (t + 1 < NT) load_regs((t + 1) * 32);
    const int buf = t & 1;
    short8 af[4], bfr[4];
#pragma unroll
    for (int i = 0; i < 4; ++i)
      af[i] = *reinterpret_cast<const short8*>(
          &As[buf][(wm + i * 16 + (lane & 15)) * 32 + (lane >> 4) * 8]);
#pragma unroll
    for (int j = 0; j < 4; ++j)
      bfr[j] = *reinterpret_cast<const short8*>(
          &Bs[buf][(wn + j * 16 + (lane & 15)) * 32 + (lane >> 4) * 8]);
#pragma unroll
    for (int i = 0; i < 4; ++i)
#pragma unroll
      for (int j = 0; j < 4; ++j)
        acc[i][j] = __builtin_amdgcn_mfma_f32_16x16x32_bf16(af[i], bfr[j], acc[i][j], 0, 0, 0);
    __syncthreads();
    if (t + 1 < NT) { write_lds((t + 1) & 1); __syncthreads(); }
  }

  // Epilogue: bias + RoPE + scatter bf16 (chunk-local rows).
  const int col_l = lane & 15;
  const int row_h = (lane >> 4) * 4;
#pragma unroll
  for (int j = 0; j < 4; ++j) {
    const int n_loc = wn + j * 16 + col_l;        // 0..127
    const int gcol  = n0 + n_loc;
    const float bias = Bv[n_loc];
    const int d    = gcol & 63;
    const int head = gcol >> 7;
    const bool is_k = (gcol >> 6) & 1;
    const bool odd = d & 1;
    const float invf = rope_invf(d >> 1);
    short* dst = is_k ? ks : qs;
#pragma unroll
    for (int i = 0; i < 4; ++i) {
#pragma unroll
      for (int r = 0; r < 4; ++r) {
        float v  = acc[i][j][r] + bias;
        float vp = __shfl_xor(v, 1, 64);
        int tl  = lrow0 + wm + i * 16 + row_h + r;   // chunk-local token row
        int pos = tl & (LQ - 1);
        float s, c;
        rope_cs(pos, invf, &s, &c);
        float o = odd ? (v * c + vp * s) : (v * c - vp * s);
        dst[(size_t)tl * QKS + head * 64 + d] = (short)f2bf(o);
      }
    }
  }
}

// ---------------------------------------------------------------------------
// Role logits chunk: block (nt, mt, bz); 60 heads, 15/wave. bf16 LDS tile,
// f32 coalesced write-out. grid: (8, 16, cb)
// ---------------------------------------------------------------------------
__global__ __launch_bounds__(256)
void k_role_chunk(const short* __restrict__ qs, const short* __restrict__ ks,
                  const void* __restrict__ triu_mask, float* __restrict__ out,
                  int b0) {
  const int nt = blockIdx.x, mt = blockIdx.y, bz = blockIdx.z;
  const int bg = b0 + bz;
  const int m0 = mt * 16, n0 = nt * 32;
  __shared__ uint16_t tile[16 * 32 * 60];   // 60 KB

  const int tid = threadIdx.x, lane = tid & 63, w = tid >> 6;
  const int frow = lane & 15;
  const int koff = (lane >> 4) * 8;

  const size_t qbase = ((size_t)bz * LQ + m0) * QKS;
  const size_t kbase = ((size_t)bz * LQ + n0) * QKS;

  for (int hh = 0; hh < 15; ++hh) {
    const int r    = w * 15 + hh;
    const int hoff = (2 + r) * 64;
    short8 aq[2], bk[2][2];
#pragma unroll
    for (int kc = 0; kc < 2; ++kc) {
      aq[kc] = *reinterpret_cast<const short8*>(
          qs + qbase + (size_t)frow * QKS + hoff + kc * 32 + koff);
#pragma unroll
      for (int jf = 0; jf < 2; ++jf)
        bk[jf][kc] = *reinterpret_cast<const short8*>(
            ks + kbase + (size_t)(jf * 16 + frow) * QKS + hoff + kc * 32 + koff);
    }
    f32x4 acc[2] = {};
#pragma unroll
    for (int jf = 0; jf < 2; ++jf)
#pragma unroll
      for (int kc = 0; kc < 2; ++kc)
        acc[jf] = __builtin_amdgcn_mfma_f32_16x16x32_bf16(aq[kc], bk[jf][kc], acc[jf], 0, 0, 0);
#pragma unroll
    for (int jf = 0; jf < 2; ++jf)
#pragma unroll
      for (int rg = 0; rg < 4; ++rg) {
        int m = (lane >> 4) * 4 + rg;
        int n = jf * 16 + (lane & 15);
        tile[(m * 32 + n) * 60 + r] = f2bf(acc[jf][rg]);
      }
  }
  __syncthreads();

  const int mode = mask_mode(triu_mask);
  const size_t maskbase = ((size_t)bg * LQ + m0) * LQ + n0;
  const size_t outbase  = ROLE_OFF + (((size_t)bg * LQ + m0) * LQ + n0) * 60;
  for (int e = tid; e < 16 * 1920; e += 256) {
    int m = e / 1920;
    int x = e - m * 1920;          // n*60 + r
    int n = x / 60;
    bool mk = mask_at(triu_mask, mode, maskbase + (size_t)m * LQ + n);
    out[outbase + (size_t)m * (LQ * 60) + x] = mk ? bf2f(tile[e]) : NEGF;
  }
}

// ---------------------------------------------------------------------------
// tri/arg logits chunk: block (mt, h, bz), 32 rows x 256. f32 write-out.
// grid: (8, 2, cb)
// ---------------------------------------------------------------------------
__global__ __launch_bounds__(256)
void k_ta_chunk(const short* __restrict__ qs, const short* __restrict__ ks,
                const void* __restrict__ word_mask, float* __restrict__ out,
                int b0) {
  const int mt = blockIdx.x, h = blockIdx.y, bz = blockIdx.z;
  const int bg = b0 + bz;
  const int m0 = mt * 32;
  __shared__ uint16_t tile[32 * 256];   // 16 KB

  const int tid = threadIdx.x, lane = tid & 63, w = tid >> 6;
  const int frow = lane & 31;
  const int koff = (lane >> 5) * 8;
  const size_t qbase = ((size_t)bz * LQ + m0) * QKS + h * 64;

  short8 aq[4];
#pragma unroll
  for (int kc = 0; kc < 4; ++kc)
    aq[kc] = *reinterpret_cast<const short8*>(
        qs + qbase + (size_t)frow * QKS + kc * 16 + koff);

  typedef __attribute__((ext_vector_type(16))) float f32x16l;
#pragma unroll
  for (int jn = 0; jn < 2; ++jn) {
    const int ncol0 = w * 64 + jn * 32;
    const size_t kb2 = ((size_t)bz * LQ + ncol0) * QKS + h * 64;
    short8 bk[4];
#pragma unroll
    for (int kc = 0; kc < 4; ++kc)
      bk[kc] = *reinterpret_cast<const short8*>(
          ks + kb2 + (size_t)frow * QKS + kc * 16 + koff);
    f32x16l acc = {};
#pragma unroll
    for (int kc = 0; kc < 4; ++kc)
      acc = __builtin_amdgcn_mfma_f32_32x32x16_bf16(aq[kc], bk[kc], acc, 0, 0, 0);
#pragma unroll
    for (int rg = 0; rg < 16; ++rg) {
      int m = (rg & 3) + 8 * (rg >> 2) + 4 * (lane >> 5);
      int n = ncol0 + (lane & 31);
      tile[m * 256 + n] = f2bf(acc[rg]);
    }
  }
  __syncthreads();

  const int mode = mask_mode(word_mask);
  const size_t maskbase = ((size_t)bg * LQ + m0) * LQ;
  const size_t outbase  = (size_t)h * TA_OFF + ((size_t)bg * LQ + m0) * LQ;
  for (int e = tid; e < 8192; e += 256) {
    int m = e >> 8, n = e & 255;
    bool mk = mask_at(word_mask, mode, maskbase + (size_t)m * LQ + n);
    out[outbase + e] = mk ? bf2f(tile[e]) : NEGF;
  }
}

// ---------------------------------------------------------------------------
// Fallback fused tri/arg (tiny ws): block (h, b). q/k in LDS, then QK^T.
// grid (2,16). f32 writes.
// ---------------------------------------------------------------------------
__global__ __launch_bounds__(256)
void k_ta_fused(const float* __restrict__ E,
                const float* __restrict__ triW, const float* __restrict__ triB,
                const float* __restrict__ argW, const float* __restrict__ argB,
                const void* __restrict__ word_mask, float* __restrict__ out) {
  const int h = blockIdx.x, b = blockIdx.y;
  const float* W  = h ? argW : triW;
  const float* Bv = h ? argB : triB;

  __shared__ short As[2][128 * 32];
  __shared__ short Bs[2][128 * 32];
  __shared__ short qk[256 * 128];          // row t: q d0..63 | k d64..127

  const int tid  = threadIdx.x;
  const int lane = tid & 63;
  const int w    = tid >> 6;
  const int wm   = (w >> 1) * 64, wn = (w & 1) * 64;
  const int srow = tid >> 2;
  const int scol = (tid & 3) * 8;
  const int col_l = lane & 15;
  const int row_h = (lane >> 4) * 4;

  for (int mi = 0; mi < 2; ++mi) {
    const int r0 = mi * 128;
    f32x4 acc[4][4] = {};
    f32x4 ra0[2], ra1[2], rb0[2], rb1[2];
    auto load_regs = [&](int k0) {
      const float* pa0 = E + ((size_t)b * LQ + r0 + srow) * HID + k0 + scol;
      const float* pa1 = E + ((size_t)b * LQ + r0 + 64 + srow) * HID + k0 + scol;
      const float* pb0 = W + (size_t)(srow) * HID + k0 + scol;
      const float* pb1 = W + (size_t)(64 + srow) * HID + k0 + scol;
      ra0[0] = *reinterpret_cast<const f32x4*>(pa0);
      ra0[1] = *reinterpret_cast<const f32x4*>(pa0 + 4);
      ra1[0] = *reinterpret_cast<const f32x4*>(pa1);
      ra1[1] = *reinterpret_cast<const f32x4*>(pa1 + 4);
      rb0[0] = *reinterpret_cast<const f32x4*>(pb0);
      rb0[1] = *reinterpret_cast<const f32x4*>(pb0 + 4);
      rb1[0] = *reinterpret_cast<const f32x4*>(pb1);
      rb1[1] = *reinterpret_cast<const f32x4*>(pb1 + 4);
    };
    auto cvt8 = [&](const f32x4* v) -> short8 {
      short8 r;
      r[0] = (short)f2bf_tr(v[0][0]); r[1] = (short)f2bf_tr(v[0][1]);
      r[2] = (short)f2bf_tr(v[0][2]); r[3] = (short)f2bf_tr(v[0][3]);
      r[4] = (short)f2bf_tr(v[1][0]); r[5] = (short)f2bf_tr(v[1][1]);
      r[6] = (short)f2bf_tr(v[1][2]); r[7] = (short)f2bf_tr(v[1][3]);
      return r;
    };
    auto write_lds = [&](int buf) {
      *reinterpret_cast<short8*>(&As[buf][srow * 32 + scol])        = cvt8(ra0);
      *reinterpret_cast<short8*>(&As[buf][(64 + srow) * 32 + scol]) = cvt8(ra1);
      *reinterpret_cast<short8*>(&Bs[buf][srow * 32 + scol])        = cvt8(rb0);
      *reinterpret_cast<short8*>(&Bs[buf][(64 + srow) * 32 + scol]) = cvt8(rb1);
    };
    load_regs(0); write_lds(0); __syncthreads();
    for (int t = 0; t < 32; ++t) {
      if (t + 1 < 32) load_regs((t + 1) * 32);
      const int buf = t & 1;
      short8 af[4], bfr[4];
#pragma unroll
      for (int i = 0; i < 4; ++i)
        af[i] = *reinterpret_cast<const short8*>(
            &As[buf][(wm + i * 16 + col_l) * 32 + (lane >> 4) * 8]);
#pragma unroll
      for (int j = 0; j < 4; ++j)
        bfr[j] = *reinterpret_cast<const short8*>(
            &Bs[buf][(wn + j * 16 + col_l) * 32 + (lane >> 4) * 8]);
#pragma unroll
      for (int i = 0; i < 4; ++i)
#pragma unroll
        for (int j = 0; j < 4; ++j)
          acc[i][j] = __builtin_amdgcn_mfma_f32_16x16x32_bf16(af[i], bfr[j], acc[i][j], 0, 0, 0);
      __syncthreads();
      if (t + 1 < 32) { write_lds((t + 1) & 1); __syncthreads(); }
    }
#pragma unroll
    for (int j = 0; j < 4; ++j) {
      const int n_loc = wn + j * 16 + col_l;      // 0..127 (q|k)
      const float bias = Bv[n_loc];
      const int d = n_loc & 63;
      const bool odd = d & 1;
      const float invf = rope_invf(d >> 1);
#pragma unroll
      for (int i = 0; i < 4; ++i) {
#pragma unroll
        for (int r = 0; r < 4; ++r) {
          float v  = acc[i][j][r] + bias;
          float vp = __shfl_xor(v, 1, 64);
          int pos = r0 + wm + i * 16 + row_h + r;
          float s, c;
          rope_cs(pos, invf, &s, &c);
          float o = odd ? (v * c + vp * s) : (v * c - vp * s);
          qk[pos * 128 + n_loc] = (short)f2bf(o);
        }
      }
    }
    __syncthreads();
  }

  const int mode = mask_mode(word_mask);
  short8 aq[4][2];
#pragma unroll
  for (int i = 0; i < 4; ++i)
#pragma unroll
    for (int kk = 0; kk < 2; ++kk)
      aq[i][kk] = *reinterpret_cast<const short8*>(
          &qk[(w * 64 + i * 16 + col_l) * 128 + kk * 32 + (lane >> 4) * 8]);

  for (int ncb = 0; ncb < 4; ++ncb) {
    const int nbase = ncb * 64;
    short8 bk[4][2];
#pragma unroll
    for (int j = 0; j < 4; ++j)
#pragma unroll
      for (int kk = 0; kk < 2; ++kk)
        bk[j][kk] = *reinterpret_cast<const short8*>(
            &qk[(nbase + j * 16 + col_l) * 128 + 64 + kk * 32 + (lane >> 4) * 8]);
    f32x4 acc[4][4] = {};
#pragma unroll
    for (int i = 0; i < 4; ++i)
#pragma unroll
      for (int j = 0; j < 4; ++j)
#pragma unroll
        for (int kk = 0; kk < 2; ++kk)
          acc[i][j] = __builtin_amdgcn_mfma_f32_16x16x32_bf16(aq[i][kk], bk[j][kk], acc[i][j], 0, 0, 0);
#pragma unroll
    for (int i = 0; i < 4; ++i)
#pragma unroll
      for (int j = 0; j < 4; ++j)
#pragma unroll
        for (int r = 0; r < 4; ++r) {
          int gm = w * 64 + i * 16 + row_h + r;
          int gn = nbase + j * 16 + col_l;
          size_t mi_ = ((size_t)b * LQ + gm) * LQ + gn;
          bool mk = mask_at(word_mask, mode, mi_);
          out[(size_t)h * TA_OFF + mi_] = mk ? acc[i][j][r] : NEGF;
        }
  }
}

// ---------------------------------------------------------------------------
extern "C" void kernel_launch(void* const* d_in, const int* in_sizes, int n_in,
                              void* d_out, int out_size, void* d_ws, size_t ws_size,
                              hipStream_t stream) {
  (void)in_sizes; (void)n_in; (void)out_size;
  const float* E     = (const float*)d_in[0];
  const float* triW  = (const float*)d_in[1];
  const float* triB  = (const float*)d_in[2];
  const float* argW  = (const float*)d_in[3];
  const float* argB  = (const float*)d_in[4];
  const float* roleW = (const float*)d_in[5];
  const float* roleB = (const float*)d_in[6];
  const void*  wmask = d_in[7];
  const void*  tmask = d_in[8];
  float* out = (float*)d_out;

  const size_t PER_B = (size_t)LQ * QKS * 2 * 2;   // q+k bytes per batch = 4,063,232
  int cb = (int)(ws_size / PER_B);
  if (cb > 16) cb = 16;

  if (cb >= 1) {
    short* qs = (short*)d_ws;
    short* ks = qs + (size_t)cb * LQ * QKS;
    for (int b0 = 0; b0 < 16; b0 += cb) {
      int cbi = (16 - b0 < cb) ? (16 - b0) : cb;
      k_proj_chunk<<<dim3(62, 2 * cbi), dim3(256), 0, stream>>>(
          E, triW, triB, argW, argB, roleW, roleB, qs, ks, b0);
      k_role_chunk<<<dim3(8, 16, cbi), dim3(256), 0, stream>>>(qs, ks, tmask, out, b0);
      k_ta_chunk<<<dim3(8, 2, cbi), dim3(256), 0, stream>>>(qs, ks, wmask, out, b0);
    }
  } else {
    // Tiny-ws fallback: scratch in d_out's tri region (f32 8.4MB > 4.1MB);
    // tri/arg recomputed last by the fused kernel.
    short* qs = (short*)d_out;
    short* ks = qs + (size_t)LQ * QKS;
    for (int b0 = 0; b0 < 16; ++b0) {
      k_proj_chunk<<<dim3(62, 2), dim3(256), 0, stream>>>(
          E, triW, triB, argW, argB, roleW, roleB, qs, ks, b0);
      k_role_chunk<<<dim3(8, 16, 1), dim3(256), 0, stream>>>(qs, ks, tmask, out, b0);
    }
    k_ta_fused<<<dim3(2, 16), dim3(256), 0, stream>>>(E, triW, triB, argW, argB,
                                                      wmask, out);
  }
}

// Round 6
// 272.103 us; speedup vs baseline: 1.4609x; 1.4609x over previous
//
#include <hip/hip_runtime.h>
#include <hip/hip_bf16.h>
#include <stdint.h>

// ---------------------------------------------------------------------------
// OneEventExtracter: proj GEMM (f32 in -> bf16 MFMA) + RoPE + 62-head QK^T.
// B=16, L=256, H=1024, heads: [tri, arg, role0..59], head_dim=64.
// Inputs f32, OUTPUTS FLOAT32. Masked slots = bf16-cast -1e12 exactly.
// R5: role kernel 512thr + f4 writes; proj via bf16 preconvert + global_load_lds.
// ---------------------------------------------------------------------------

typedef __attribute__((ext_vector_type(8)))  short short8;
typedef __attribute__((ext_vector_type(4)))  float f32x4;
typedef __attribute__((ext_vector_type(4)))  uint16_t u16x4;

#define LQ    256
#define HID   1024
#define QKS   3968                 // 62 heads * 64
#define NEGF  (-1000727379968.0f)  // bf16(-1e12) as f32 — matches bf16-cast ref
#define TA_OFF   1048576ULL        // arg output offset (f32 elems)
#define ROLE_OFF 2097152ULL        // role output offset (f32 elems)

__device__ __forceinline__ uint16_t f2bf(float x) {          // RNE
  uint32_t u = __builtin_bit_cast(uint32_t, x);
  return (uint16_t)((u + 0x7FFFu + ((u >> 16) & 1u)) >> 16);
}
__device__ __forceinline__ uint16_t f2bf_tr(float x) {       // truncate (GEMM in)
  return (uint16_t)(__builtin_bit_cast(uint32_t, x) >> 16);
}
__device__ __forceinline__ float bf2f(uint16_t b) {
  uint32_t u = ((uint32_t)b) << 16;
  return __builtin_bit_cast(float, u);
}
__device__ __forceinline__ int mask_mode(const void* p) {
  uint32_t w0 = *(const uint32_t*)p;
  if (w0 == 0x01010101u) return 0;   // bool bytes
  if (w0 == 1u)          return 1;   // int32
  if (w0 == 0x3F803F80u) return 2;   // bf16
  return 3;                          // f32
}
__device__ __forceinline__ bool mask_at(const void* p, int mode, size_t idx) {
  if (mode == 0) return ((const uint8_t*)p)[idx] != 0;
  if (mode == 1) return ((const int*)p)[idx] != 0;
  if (mode == 2) return (((const uint16_t*)p)[idx] & 0x7FFFu) != 0;
  return ((const float*)p)[idx] != 0.0f;
}
__device__ __forceinline__ void rope_cs(int pos, float invf, float* s, float* c) {
  float ang = (float)pos * invf;
  __sincosf(ang, s, c);
}
__device__ __forceinline__ float rope_invf(int p) {
  return exp2f(-(float)p * (13.287712379549449f / 32.0f));
}
__device__ __forceinline__ void gload16(const short* g, short* l) {
  __builtin_amdgcn_global_load_lds(
      (const __attribute__((address_space(1))) void*)g,
      (__attribute__((address_space(3))) void*)l, 16, 0, 0);
}

// ---------------------------------------------------------------------------
// Preconvert: E[4096x1024] f32 -> Eb bf16; {tri|arg|role}W -> Wb[7936][1024]
// bf16 concatenated in output-column order.
// ---------------------------------------------------------------------------
#define EGRP 524288                    // 4096*1024/8
#define WGRP 1015808                   // 7936*1024/8
__global__ __launch_bounds__(256)
void k_preconv(const float* __restrict__ E,
               const float* __restrict__ triW, const float* __restrict__ argW,
               const float* __restrict__ roleW,
               short* __restrict__ Eb, short* __restrict__ Wb) {
  for (int gid = blockIdx.x * 256 + threadIdx.x; gid < EGRP + WGRP;
       gid += gridDim.x * 256) {
    const float* src;
    short* dst;
    if (gid < EGRP) {
      src = E + (size_t)gid * 8;
      dst = Eb + (size_t)gid * 8;
    } else {
      int g = gid - EGRP;
      int row = g >> 7;                // 128 groups of 8 per 1024-row
      int col8 = g & 127;
      const float* srow = (row < 128) ? triW + (size_t)row * HID
                        : (row < 256) ? argW + (size_t)(row - 128) * HID
                                      : roleW + (size_t)(row - 256) * HID;
      src = srow + col8 * 8;
      dst = Wb + (size_t)row * HID + col8 * 8;
    }
    f32x4 v0 = *reinterpret_cast<const f32x4*>(src);
    f32x4 v1 = *reinterpret_cast<const f32x4*>(src + 4);
    short8 r;
    r[0] = (short)f2bf_tr(v0[0]); r[1] = (short)f2bf_tr(v0[1]);
    r[2] = (short)f2bf_tr(v0[2]); r[3] = (short)f2bf_tr(v0[3]);
    r[4] = (short)f2bf_tr(v1[0]); r[5] = (short)f2bf_tr(v1[1]);
    r[6] = (short)f2bf_tr(v1[2]); r[7] = (short)f2bf_tr(v1[3]);
    *reinterpret_cast<short8*>(dst) = r;
  }
}

// ---------------------------------------------------------------------------
// Proj GEMM (preconverted bf16, global_load_lds staging): 128x128 tile, BK=32.
// grid: (62, 2*cb). RoPE epilogue -> qs/ks bf16 scratch (chunk-local rows).
// ---------------------------------------------------------------------------
__global__ __launch_bounds__(256)
void k_proj_pre(const short* __restrict__ Eb, const short* __restrict__ Wb,
                const float* __restrict__ triB, const float* __restrict__ argB,
                const float* __restrict__ roleB,
                short* __restrict__ qs, short* __restrict__ ks, int b0) {
  const int nb = blockIdx.x;          // 0..61
  const int mb = blockIdx.y;
  const int n0 = nb * 128;
  const int mrow0 = b0 * LQ + mb * 128;
  const int lrow0 = mb * 128;

  const float* Bv;
  if (nb == 0)      Bv = triB;
  else if (nb == 1) Bv = argB;
  else              Bv = roleB + (n0 - 256);

  __shared__ short As[2][128 * 32];
  __shared__ short Bs[2][128 * 32];

  const int tid  = threadIdx.x;
  const int lane = tid & 63;
  const int w    = tid >> 6;
  const int wm   = (w >> 1) * 64, wn = (w & 1) * 64;
  const int srr  = lane >> 2;          // 0..15 row within chunk
  const int src8 = (lane & 3) * 8;     // col offset

  f32x4 acc[4][4] = {};

  auto stage = [&](int buf, int k0) {
#pragma unroll
    for (int cc = 0; cc < 2; ++cc) {
      const int c = w * 2 + cc;        // chunk 0..7 (16 rows each)
      gload16(Eb + (size_t)(mrow0 + c * 16 + srr) * HID + k0 + src8,
              &As[buf][c * 512]);
      gload16(Wb + (size_t)(n0 + c * 16 + srr) * HID + k0 + src8,
              &Bs[buf][c * 512]);
    }
  };

  stage(0, 0);
  __syncthreads();
  const int NT = HID / 32;
  for (int t = 0; t < NT; ++t) {
    const int buf = t & 1;
    if (t + 1 < NT) stage(buf ^ 1, (t + 1) * 32);
    short8 af[4], bfr[4];
#pragma unroll
    for (int i = 0; i < 4; ++i)
      af[i] = *reinterpret_cast<const short8*>(
          &As[buf][(wm + i * 16 + (lane & 15)) * 32 + (lane >> 4) * 8]);
#pragma unroll
    for (int j = 0; j < 4; ++j)
      bfr[j] = *reinterpret_cast<const short8*>(
          &Bs[buf][(wn + j * 16 + (lane & 15)) * 32 + (lane >> 4) * 8]);
#pragma unroll
    for (int i = 0; i < 4; ++i)
#pragma unroll
      for (int j = 0; j < 4; ++j)
        acc[i][j] = __builtin_amdgcn_mfma_f32_16x16x32_bf16(af[i], bfr[j], acc[i][j], 0, 0, 0);
    __syncthreads();
  }

  // Epilogue: bias + RoPE + scatter bf16.
  const int col_l = lane & 15;
  const int row_h = (lane >> 4) * 4;
#pragma unroll
  for (int j = 0; j < 4; ++j) {
    const int n_loc = wn + j * 16 + col_l;
    const int gcol  = n0 + n_loc;
    const float bias = Bv[n_loc];
    const int d    = gcol & 63;
    const int head = gcol >> 7;
    const bool is_k = (gcol >> 6) & 1;
    const bool odd = d & 1;
    const float invf = rope_invf(d >> 1);
    short* dst = is_k ? ks : qs;
#pragma unroll
    for (int i = 0; i < 4; ++i) {
#pragma unroll
      for (int r = 0; r < 4; ++r) {
        float v  = acc[i][j][r] + bias;
        float vp = __shfl_xor(v, 1, 64);
        int tl  = lrow0 + wm + i * 16 + row_h + r;
        int pos = tl & (LQ - 1);
        float s, c;
        rope_cs(pos, invf, &s, &c);
        float o = odd ? (v * c + vp * s) : (v * c - vp * s);
        dst[(size_t)tl * QKS + head * 64 + d] = (short)f2bf(o);
      }
    }
  }
}

// ---------------------------------------------------------------------------
// Fallback proj (f32 inputs, reg-staged cvt) — proven path, used if ws small.
// ---------------------------------------------------------------------------
__global__ __launch_bounds__(256)
void k_proj_chunk(const float* __restrict__ E,
                  const float* __restrict__ triW, const float* __restrict__ triB,
                  const float* __restrict__ argW, const float* __restrict__ argB,
                  const float* __restrict__ roleW, const float* __restrict__ roleB,
                  short* __restrict__ qs, short* __restrict__ ks, int b0) {
  const int nb = blockIdx.x;
  const int mb = blockIdx.y;
  const int n0 = nb * 128;
  const int mrow0 = b0 * LQ + mb * 128;
  const int lrow0 = mb * 128;

  const float* W;  const float* Bv;
  if (nb == 0)      { W = triW;                             Bv = triB; }
  else if (nb == 1) { W = argW;                             Bv = argB; }
  else              { W = roleW + (size_t)(n0 - 256) * HID; Bv = roleB + (n0 - 256); }

  __shared__ short As[2][128 * 32];
  __shared__ short Bs[2][128 * 32];

  const int tid  = threadIdx.x;
  const int lane = tid & 63;
  const int w    = tid >> 6;
  const int wm   = (w >> 1) * 64, wn = (w & 1) * 64;
  const int srow = tid >> 2;
  const int scol = (tid & 3) * 8;

  f32x4 acc[4][4] = {};
  f32x4 ra0[2], ra1[2], rb0[2], rb1[2];

  auto load_regs = [&](int k0) {
    const float* pa0 = E + (size_t)(mrow0 + srow) * HID + k0 + scol;
    const float* pa1 = E + (size_t)(mrow0 + 64 + srow) * HID + k0 + scol;
    const float* pb0 = W + (size_t)(srow) * HID + k0 + scol;
    const float* pb1 = W + (size_t)(64 + srow) * HID + k0 + scol;
    ra0[0] = *reinterpret_cast<const f32x4*>(pa0);
    ra0[1] = *reinterpret_cast<const f32x4*>(pa0 + 4);
    ra1[0] = *reinterpret_cast<const f32x4*>(pa1);
    ra1[1] = *reinterpret_cast<const f32x4*>(pa1 + 4);
    rb0[0] = *reinterpret_cast<const f32x4*>(pb0);
    rb0[1] = *reinterpret_cast<const f32x4*>(pb0 + 4);
    rb1[0] = *reinterpret_cast<const f32x4*>(pb1);
    rb1[1] = *reinterpret_cast<const f32x4*>(pb1 + 4);
  };
  auto cvt8 = [&](const f32x4* v) -> short8 {
    short8 r;
    r[0] = (short)f2bf_tr(v[0][0]); r[1] = (short)f2bf_tr(v[0][1]);
    r[2] = (short)f2bf_tr(v[0][2]); r[3] = (short)f2bf_tr(v[0][3]);
    r[4] = (short)f2bf_tr(v[1][0]); r[5] = (short)f2bf_tr(v[1][1]);
    r[6] = (short)f2bf_tr(v[1][2]); r[7] = (short)f2bf_tr(v[1][3]);
    return r;
  };
  auto write_lds = [&](int buf) {
    *reinterpret_cast<short8*>(&As[buf][srow * 32 + scol])        = cvt8(ra0);
    *reinterpret_cast<short8*>(&As[buf][(64 + srow) * 32 + scol]) = cvt8(ra1);
    *reinterpret_cast<short8*>(&Bs[buf][srow * 32 + scol])        = cvt8(rb0);
    *reinterpret_cast<short8*>(&Bs[buf][(64 + srow) * 32 + scol]) = cvt8(rb1);
  };

  load_regs(0); write_lds(0); __syncthreads();
  const int NT = HID / 32;
  for (int t = 0; t < NT; ++t) {
    if (t + 1 < NT) load_regs((t + 1) * 32);
    const int buf = t & 1;
    short8 af[4], bfr[4];
#pragma unroll
    for (int i = 0; i < 4; ++i)
      af[i] = *reinterpret_cast<const short8*>(
          &As[buf][(wm + i * 16 + (lane & 15)) * 32 + (lane >> 4) * 8]);
#pragma unroll
    for (int j = 0; j < 4; ++j)
      bfr[j] = *reinterpret_cast<const short8*>(
          &Bs[buf][(wn + j * 16 + (lane & 15)) * 32 + (lane >> 4) * 8]);
#pragma unroll
    for (int i = 0; i < 4; ++i)
#pragma unroll
      for (int j = 0; j < 4; ++j)
        acc[i][j] = __builtin_amdgcn_mfma_f32_16x16x32_bf16(af[i], bfr[j], acc[i][j], 0, 0, 0);
    __syncthreads();
    if (t + 1 < NT) { write_lds((t + 1) & 1); __syncthreads(); }
  }

  const int col_l = lane & 15;
  const int row_h = (lane >> 4) * 4;
#pragma unroll
  for (int j = 0; j < 4; ++j) {
    const int n_loc = wn + j * 16 + col_l;
    const int gcol  = n0 + n_loc;
    const float bias = Bv[n_loc];
    const int d    = gcol & 63;
    const int head = gcol >> 7;
    const bool is_k = (gcol >> 6) & 1;
    const bool odd = d & 1;
    const float invf = rope_invf(d >> 1);
    short* dst = is_k ? ks : qs;
#pragma unroll
    for (int i = 0; i < 4; ++i) {
#pragma unroll
      for (int r = 0; r < 4; ++r) {
        float v  = acc[i][j][r] + bias;
        float vp = __shfl_xor(v, 1, 64);
        int tl  = lrow0 + wm + i * 16 + row_h + r;
        int pos = tl & (LQ - 1);
        float s, c;
        rope_cs(pos, invf, &s, &c);
        float o = odd ? (v * c + vp * s) : (v * c - vp * s);
        dst[(size_t)tl * QKS + head * 64 + d] = (short)f2bf(o);
      }
    }
  }
}

// ---------------------------------------------------------------------------
// Role logits v2: 512 threads (8 waves), heads {8,8,8,8,7,7,7,7} per wave.
// bf16 LDS tile [16][32][60] -> float4 coalesced f32 write-out.
// grid: (8, 16, cb)
// ---------------------------------------------------------------------------
__global__ __launch_bounds__(512)
void k_role2(const short* __restrict__ qs, const short* __restrict__ ks,
             const void* __restrict__ triu_mask, float* __restrict__ out,
             int b0) {
  const int nt = blockIdx.x, mt = blockIdx.y, bz = blockIdx.z;
  const int bg = b0 + bz;
  const int m0 = mt * 16, n0 = nt * 32;
  __shared__ uint16_t tile[16 * 32 * 60];   // 60 KB

  const int tid = threadIdx.x, lane = tid & 63, w = tid >> 6;
  const int frow = lane & 15;
  const int koff = (lane >> 4) * 8;
  const int hstart = (w < 4) ? w * 8 : 32 + (w - 4) * 7;
  const int hcnt   = (w < 4) ? 8 : 7;

  const size_t qbase = ((size_t)bz * LQ + m0) * QKS;
  const size_t kbase = ((size_t)bz * LQ + n0) * QKS;

  for (int i = 0; i < hcnt; ++i) {
    const int r    = hstart + i;
    const int hoff = (2 + r) * 64;
    short8 aq[2], bk[2][2];
#pragma unroll
    for (int kc = 0; kc < 2; ++kc) {
      aq[kc] = *reinterpret_cast<const short8*>(
          qs + qbase + (size_t)frow * QKS + hoff + kc * 32 + koff);
#pragma unroll
      for (int jf = 0; jf < 2; ++jf)
        bk[jf][kc] = *reinterpret_cast<const short8*>(
            ks + kbase + (size_t)(jf * 16 + frow) * QKS + hoff + kc * 32 + koff);
    }
    f32x4 acc[2] = {};
#pragma unroll
    for (int jf = 0; jf < 2; ++jf)
#pragma unroll
      for (int kc = 0; kc < 2; ++kc)
        acc[jf] = __builtin_amdgcn_mfma_f32_16x16x32_bf16(aq[kc], bk[jf][kc], acc[jf], 0, 0, 0);
#pragma unroll
    for (int jf = 0; jf < 2; ++jf)
#pragma unroll
      for (int rg = 0; rg < 4; ++rg) {
        int m = (lane >> 4) * 4 + rg;
        int n = jf * 16 + (lane & 15);
        tile[(m * 32 + n) * 60 + r] = f2bf(acc[jf][rg]);
      }
  }
  __syncthreads();

  const int mode = mask_mode(triu_mask);
  const size_t maskbase = ((size_t)bg * LQ + m0) * LQ + n0;
  const size_t outbase  = ROLE_OFF + (((size_t)bg * LQ + m0) * LQ + n0) * 60;
  for (int f = tid; f < 7680; f += 512) {         // 16*1920/4 float4s
    int e  = f * 4;
    int m  = e / 1920;
    int x  = e - m * 1920;           // n_loc*60 + r
    int n_ = x / 60;
    int rr = x - n_ * 60;
    u16x4 tv = *reinterpret_cast<const u16x4*>(&tile[e]);
    f32x4 v;
    if (rr <= 56) {
      bool mk = mask_at(triu_mask, mode, maskbase + (size_t)m * LQ + n_);
      v[0] = mk ? bf2f(tv[0]) : NEGF;
      v[1] = mk ? bf2f(tv[1]) : NEGF;
      v[2] = mk ? bf2f(tv[2]) : NEGF;
      v[3] = mk ? bf2f(tv[3]) : NEGF;
    } else {
#pragma unroll
      for (int q = 0; q < 4; ++q) {
        int nq = (x + q) / 60;
        bool mk = mask_at(triu_mask, mode, maskbase + (size_t)m * LQ + nq);
        v[q] = mk ? bf2f(tv[q]) : NEGF;
      }
    }
    *reinterpret_cast<f32x4*>(&out[outbase + (size_t)m * (LQ * 60) + x]) = v;
  }
}

// ---------------------------------------------------------------------------
// tri/arg logits chunk: block (mt, h, bz), 32 rows x 256. grid: (8, 2, cb)
// ---------------------------------------------------------------------------
__global__ __launch_bounds__(256)
void k_ta_chunk(const short* __restrict__ qs, const short* __restrict__ ks,
                const void* __restrict__ word_mask, float* __restrict__ out,
                int b0) {
  const int mt = blockIdx.x, h = blockIdx.y, bz = blockIdx.z;
  const int bg = b0 + bz;
  const int m0 = mt * 32;
  __shared__ uint16_t tile[32 * 256];

  const int tid = threadIdx.x, lane = tid & 63, w = tid >> 6;
  const int frow = lane & 31;
  const int koff = (lane >> 5) * 8;
  const size_t qbase = ((size_t)bz * LQ + m0) * QKS + h * 64;

  short8 aq[4];
#pragma unroll
  for (int kc = 0; kc < 4; ++kc)
    aq[kc] = *reinterpret_cast<const short8*>(
        qs + qbase + (size_t)frow * QKS + kc * 16 + koff);

  typedef __attribute__((ext_vector_type(16))) float f32x16l;
#pragma unroll
  for (int jn = 0; jn < 2; ++jn) {
    const int ncol0 = w * 64 + jn * 32;
    const size_t kb2 = ((size_t)bz * LQ + ncol0) * QKS + h * 64;
    short8 bk[4];
#pragma unroll
    for (int kc = 0; kc < 4; ++kc)
      bk[kc] = *reinterpret_cast<const short8*>(
          ks + kb2 + (size_t)frow * QKS + kc * 16 + koff);
    f32x16l acc = {};
#pragma unroll
    for (int kc = 0; kc < 4; ++kc)
      acc = __builtin_amdgcn_mfma_f32_32x32x16_bf16(aq[kc], bk[kc], acc, 0, 0, 0);
#pragma unroll
    for (int rg = 0; rg < 16; ++rg) {
      int m = (rg & 3) + 8 * (rg >> 2) + 4 * (lane >> 5);
      int n = ncol0 + (lane & 31);
      tile[m * 256 + n] = f2bf(acc[rg]);
    }
  }
  __syncthreads();

  const int mode = mask_mode(word_mask);
  const size_t maskbase = ((size_t)bg * LQ + m0) * LQ;
  const size_t outbase  = (size_t)h * TA_OFF + ((size_t)bg * LQ + m0) * LQ;
  for (int e = tid; e < 8192; e += 256) {
    int m = e >> 8, n = e & 255;
    bool mk = mask_at(word_mask, mode, maskbase + (size_t)m * LQ + n);
    out[outbase + e] = mk ? bf2f(tile[e]) : NEGF;
  }
}

// ---------------------------------------------------------------------------
// Fallback fused tri/arg (tiny ws): unchanged proven path.
// ---------------------------------------------------------------------------
__global__ __launch_bounds__(256)
void k_ta_fused(const float* __restrict__ E,
                const float* __restrict__ triW, const float* __restrict__ triB,
                const float* __restrict__ argW, const float* __restrict__ argB,
                const void* __restrict__ word_mask, float* __restrict__ out) {
  const int h = blockIdx.x, b = blockIdx.y;
  const float* W  = h ? argW : triW;
  const float* Bv = h ? argB : triB;

  __shared__ short As[2][128 * 32];
  __shared__ short Bs[2][128 * 32];
  __shared__ short qk[256 * 128];

  const int tid  = threadIdx.x;
  const int lane = tid & 63;
  const int w    = tid >> 6;
  const int wm   = (w >> 1) * 64, wn = (w & 1) * 64;
  const int srow = tid >> 2;
  const int scol = (tid & 3) * 8;
  const int col_l = lane & 15;
  const int row_h = (lane >> 4) * 4;

  for (int mi = 0; mi < 2; ++mi) {
    const int r0 = mi * 128;
    f32x4 acc[4][4] = {};
    f32x4 ra0[2], ra1[2], rb0[2], rb1[2];
    auto load_regs = [&](int k0) {
      const float* pa0 = E + ((size_t)b * LQ + r0 + srow) * HID + k0 + scol;
      const float* pa1 = E + ((size_t)b * LQ + r0 + 64 + srow) * HID + k0 + scol;
      const float* pb0 = W + (size_t)(srow) * HID + k0 + scol;
      const float* pb1 = W + (size_t)(64 + srow) * HID + k0 + scol;
      ra0[0] = *reinterpret_cast<const f32x4*>(pa0);
      ra0[1] = *reinterpret_cast<const f32x4*>(pa0 + 4);
      ra1[0] = *reinterpret_cast<const f32x4*>(pa1);
      ra1[1] = *reinterpret_cast<const f32x4*>(pa1 + 4);
      rb0[0] = *reinterpret_cast<const f32x4*>(pb0);
      rb0[1] = *reinterpret_cast<const f32x4*>(pb0 + 4);
      rb1[0] = *reinterpret_cast<const f32x4*>(pb1);
      rb1[1] = *reinterpret_cast<const f32x4*>(pb1 + 4);
    };
    auto cvt8 = [&](const f32x4* v) -> short8 {
      short8 r;
      r[0] = (short)f2bf_tr(v[0][0]); r[1] = (short)f2bf_tr(v[0][1]);
      r[2] = (short)f2bf_tr(v[0][2]); r[3] = (short)f2bf_tr(v[0][3]);
      r[4] = (short)f2bf_tr(v[1][0]); r[5] = (short)f2bf_tr(v[1][1]);
      r[6] = (short)f2bf_tr(v[1][2]); r[7] = (short)f2bf_tr(v[1][3]);
      return r;
    };
    auto write_lds = [&](int buf) {
      *reinterpret_cast<short8*>(&As[buf][srow * 32 + scol])        = cvt8(ra0);
      *reinterpret_cast<short8*>(&As[buf][(64 + srow) * 32 + scol]) = cvt8(ra1);
      *reinterpret_cast<short8*>(&Bs[buf][srow * 32 + scol])        = cvt8(rb0);
      *reinterpret_cast<short8*>(&Bs[buf][(64 + srow) * 32 + scol]) = cvt8(rb1);
    };
    load_regs(0); write_lds(0); __syncthreads();
    for (int t = 0; t < 32; ++t) {
      if (t + 1 < 32) load_regs((t + 1) * 32);
      const int buf = t & 1;
      short8 af[4], bfr[4];
#pragma unroll
      for (int i = 0; i < 4; ++i)
        af[i] = *reinterpret_cast<const short8*>(
            &As[buf][(wm + i * 16 + col_l) * 32 + (lane >> 4) * 8]);
#pragma unroll
      for (int j = 0; j < 4; ++j)
        bfr[j] = *reinterpret_cast<const short8*>(
            &Bs[buf][(wn + j * 16 + col_l) * 32 + (lane >> 4) * 8]);
#pragma unroll
      for (int i = 0; i < 4; ++i)
#pragma unroll
        for (int j = 0; j < 4; ++j)
          acc[i][j] = __builtin_amdgcn_mfma_f32_16x16x32_bf16(af[i], bfr[j], acc[i][j], 0, 0, 0);
      __syncthreads();
      if (t + 1 < 32) { write_lds((t + 1) & 1); __syncthreads(); }
    }
#pragma unroll
    for (int j = 0; j < 4; ++j) {
      const int n_loc = wn + j * 16 + col_l;
      const float bias = Bv[n_loc];
      const int d = n_loc & 63;
      const bool odd = d & 1;
      const float invf = rope_invf(d >> 1);
#pragma unroll
      for (int i = 0; i < 4; ++i) {
#pragma unroll
        for (int r = 0; r < 4; ++r) {
          float v  = acc[i][j][r] + bias;
          float vp = __shfl_xor(v, 1, 64);
          int pos = r0 + wm + i * 16 + row_h + r;
          float s, c;
          rope_cs(pos, invf, &s, &c);
          float o = odd ? (v * c + vp * s) : (v * c - vp * s);
          qk[pos * 128 + n_loc] = (short)f2bf(o);
        }
      }
    }
    __syncthreads();
  }

  const int mode = mask_mode(word_mask);
  short8 aq[4][2];
#pragma unroll
  for (int i = 0; i < 4; ++i)
#pragma unroll
    for (int kk = 0; kk < 2; ++kk)
      aq[i][kk] = *reinterpret_cast<const short8*>(
          &qk[(w * 64 + i * 16 + col_l) * 128 + kk * 32 + (lane >> 4) * 8]);

  for (int ncb = 0; ncb < 4; ++ncb) {
    const int nbase = ncb * 64;
    short8 bk[4][2];
#pragma unroll
    for (int j = 0; j < 4; ++j)
#pragma unroll
      for (int kk = 0; kk < 2; ++kk)
        bk[j][kk] = *reinterpret_cast<const short8*>(
            &qk[(nbase + j * 16 + col_l) * 128 + 64 + kk * 32 + (lane >> 4) * 8]);
    f32x4 acc[4][4] = {};
#pragma unroll
    for (int i = 0; i < 4; ++i)
#pragma unroll
      for (int j = 0; j < 4; ++j)
#pragma unroll
        for (int kk = 0; kk < 2; ++kk)
          acc[i][j] = __builtin_amdgcn_mfma_f32_16x16x32_bf16(aq[i][kk], bk[j][kk], acc[i][j], 0, 0, 0);
#pragma unroll
    for (int i = 0; i < 4; ++i)
#pragma unroll
      for (int j = 0; j < 4; ++j)
#pragma unroll
        for (int r = 0; r < 4; ++r) {
          int gm = w * 64 + i * 16 + row_h + r;
          int gn = nbase + j * 16 + col_l;
          size_t mi_ = ((size_t)b * LQ + gm) * LQ + gn;
          bool mk = mask_at(word_mask, mode, mi_);
          out[(size_t)h * TA_OFF + mi_] = mk ? acc[i][j][r] : NEGF;
        }
  }
}

// ---------------------------------------------------------------------------
extern "C" void kernel_launch(void* const* d_in, const int* in_sizes, int n_in,
                              void* d_out, int out_size, void* d_ws, size_t ws_size,
                              hipStream_t stream) {
  (void)in_sizes; (void)n_in; (void)out_size;
  const float* E     = (const float*)d_in[0];
  const float* triW  = (const float*)d_in[1];
  const float* triB  = (const float*)d_in[2];
  const float* argW  = (const float*)d_in[3];
  const float* argB  = (const float*)d_in[4];
  const float* roleW = (const float*)d_in[5];
  const float* roleB = (const float*)d_in[6];
  const void*  wmask = d_in[7];
  const void*  tmask = d_in[8];
  float* out = (float*)d_out;

  const size_t PER_B = (size_t)LQ * QKS * 2 * 2;               // 4,063,232 B
  const size_t PRE   = ((size_t)4096 * HID + (size_t)7936 * HID) * 2;  // 24.65 MB

  int cb_pre = (ws_size > PRE) ? (int)((ws_size - PRE) / PER_B) : 0;
  if (cb_pre > 16) cb_pre = 16;

  if (cb_pre >= 1) {
    // Fast path: bf16 preconvert + global_load_lds proj.
    short* qs = (short*)d_ws;
    short* ks = qs + (size_t)cb_pre * LQ * QKS;
    short* Eb = ks + (size_t)cb_pre * LQ * QKS;
    short* Wb = Eb + (size_t)4096 * HID;
    k_preconv<<<dim3(2048), dim3(256), 0, stream>>>(E, triW, argW, roleW, Eb, Wb);
    for (int b0 = 0; b0 < 16; b0 += cb_pre) {
      int cbi = (16 - b0 < cb_pre) ? (16 - b0) : cb_pre;
      k_proj_pre<<<dim3(62, 2 * cbi), dim3(256), 0, stream>>>(
          Eb, Wb, triB, argB, roleB, qs, ks, b0);
      k_role2<<<dim3(8, 16, cbi), dim3(512), 0, stream>>>(qs, ks, tmask, out, b0);
      k_ta_chunk<<<dim3(8, 2, cbi), dim3(256), 0, stream>>>(qs, ks, wmask, out, b0);
    }
    return;
  }

  int cb = (int)(ws_size / PER_B);
  if (cb > 16) cb = 16;
  if (cb >= 1) {
    short* qs = (short*)d_ws;
    short* ks = qs + (size_t)cb * LQ * QKS;
    for (int b0 = 0; b0 < 16; b0 += cb) {
      int cbi = (16 - b0 < cb) ? (16 - b0) : cb;
      k_proj_chunk<<<dim3(62, 2 * cbi), dim3(256), 0, stream>>>(
          E, triW, triB, argW, argB, roleW, roleB, qs, ks, b0);
      k_role2<<<dim3(8, 16, cbi), dim3(512), 0, stream>>>(qs, ks, tmask, out, b0);
      k_ta_chunk<<<dim3(8, 2, cbi), dim3(256), 0, stream>>>(qs, ks, wmask, out, b0);
    }
  } else {
    short* qs = (short*)d_out;
    short* ks = qs + (size_t)LQ * QKS;
    for (int b0 = 0; b0 < 16; ++b0) {
      k_proj_chunk<<<dim3(62, 2), dim3(256), 0, stream>>>(
          E, triW, triB, argW, argB, roleW, roleB, qs, ks, b0);
      k_role2<<<dim3(8, 16, 1), dim3(512), 0, stream>>>(qs, ks, tmask, out, b0);
    }
    k_ta_fused<<<dim3(2, 16), dim3(256), 0, stream>>>(E, triW, triB, argW, argB,
                                                      wmask, out);
  }
}

// Round 7
// 269.936 us; speedup vs baseline: 1.4726x; 1.0080x over previous
//
#include <hip/hip_runtime.h>
#include <hip/hip_bf16.h>
#include <stdint.h>

// ---------------------------------------------------------------------------
// OneEventExtracter: proj GEMM (f32 in -> bf16 MFMA) + RoPE + 62-head QK^T.
// B=16, L=256, H=1024, heads: [tri, arg, role0..59], head_dim=64.
// Inputs f32, OUTPUTS FLOAT32. Masked slots = bf16-cast -1e12 exactly.
// R7: scratch q/k relaid as [chunk][head][token][64] (contiguous head frags);
//     preconv emits 1KB-tiled Eb/Wb so each proj gload_lds is one contiguous
//     1KB wave burst; role head-loop fixed-trip unroll; dead branch removed.
// ---------------------------------------------------------------------------

typedef __attribute__((ext_vector_type(8)))  short short8;
typedef __attribute__((ext_vector_type(4)))  float f32x4;
typedef __attribute__((ext_vector_type(4)))  uint16_t u16x4;

#define LQ    256
#define HID   1024
#define NH    62                   // heads
#define HSTR  16384                // 256 tokens * 64 dims, per head per batch
#define NEGF  (-1000727379968.0f)  // bf16(-1e12) as f32 — matches bf16-cast ref
#define TA_OFF   1048576ULL        // arg output offset (f32 elems)
#define ROLE_OFF 2097152ULL        // role output offset (f32 elems)

__device__ __forceinline__ uint16_t f2bf(float x) {          // RNE
  uint32_t u = __builtin_bit_cast(uint32_t, x);
  return (uint16_t)((u + 0x7FFFu + ((u >> 16) & 1u)) >> 16);
}
__device__ __forceinline__ uint16_t f2bf_tr(float x) {       // truncate (GEMM in)
  return (uint16_t)(__builtin_bit_cast(uint32_t, x) >> 16);
}
__device__ __forceinline__ float bf2f(uint16_t b) {
  uint32_t u = ((uint32_t)b) << 16;
  return __builtin_bit_cast(float, u);
}
__device__ __forceinline__ int mask_mode(const void* p) {
  uint32_t w0 = *(const uint32_t*)p;
  if (w0 == 0x01010101u) return 0;   // bool bytes
  if (w0 == 1u)          return 1;   // int32
  if (w0 == 0x3F803F80u) return 2;   // bf16
  return 3;                          // f32
}
__device__ __forceinline__ bool mask_at(const void* p, int mode, size_t idx) {
  if (mode == 0) return ((const uint8_t*)p)[idx] != 0;
  if (mode == 1) return ((const int*)p)[idx] != 0;
  if (mode == 2) return (((const uint16_t*)p)[idx] & 0x7FFFu) != 0;
  return ((const float*)p)[idx] != 0.0f;
}
__device__ __forceinline__ void rope_cs(int pos, float invf, float* s, float* c) {
  float ang = (float)pos * invf;
  __sincosf(ang, s, c);
}
__device__ __forceinline__ float rope_invf(int p) {
  return exp2f(-(float)p * (13.287712379549449f / 32.0f));
}
__device__ __forceinline__ void gload16(const short* g, short* l) {
  __builtin_amdgcn_global_load_lds(
      (const __attribute__((address_space(1))) void*)g,
      (__attribute__((address_space(3))) void*)l, 16, 0, 0);
}

// ---------------------------------------------------------------------------
// Preconvert to TILED bf16: tile = [16 rows][32 k] = 512 elems = 1KB.
// Eb[(row>>4)*32 + (k>>5)][(row&15)*32 + (k&31)]  (4096 rows, 32 k-tiles)
// Wb same with 7936 rows (tri|arg|role order).
// ---------------------------------------------------------------------------
#define EGRP 524288                    // 4096*1024/8
#define WGRP 1015808                   // 7936*1024/8
__global__ __launch_bounds__(256)
void k_preconv(const float* __restrict__ E,
               const float* __restrict__ triW, const float* __restrict__ argW,
               const float* __restrict__ roleW,
               short* __restrict__ Eb, short* __restrict__ Wb) {
  for (int gid = blockIdx.x * 256 + threadIdx.x; gid < EGRP + WGRP;
       gid += gridDim.x * 256) {
    const float* src;
    short* dst;
    if (gid < EGRP) {
      int row = gid >> 7, col8 = gid & 127;
      src = E + (size_t)row * HID + col8 * 8;
      dst = Eb + (((size_t)(row >> 4)) * 32 + (col8 >> 2)) * 512
               + (row & 15) * 32 + (col8 & 3) * 8;
    } else {
      int g = gid - EGRP;
      int row = g >> 7, col8 = g & 127;
      const float* srow = (row < 128) ? triW + (size_t)row * HID
                        : (row < 256) ? argW + (size_t)(row - 128) * HID
                                      : roleW + (size_t)(row - 256) * HID;
      src = srow + col8 * 8;
      dst = Wb + (((size_t)(row >> 4)) * 32 + (col8 >> 2)) * 512
               + (row & 15) * 32 + (col8 & 3) * 8;
    }
    f32x4 v0 = *reinterpret_cast<const f32x4*>(src);
    f32x4 v1 = *reinterpret_cast<const f32x4*>(src + 4);
    short8 r;
    r[0] = (short)f2bf_tr(v0[0]); r[1] = (short)f2bf_tr(v0[1]);
    r[2] = (short)f2bf_tr(v0[2]); r[3] = (short)f2bf_tr(v0[3]);
    r[4] = (short)f2bf_tr(v1[0]); r[5] = (short)f2bf_tr(v1[1]);
    r[6] = (short)f2bf_tr(v1[2]); r[7] = (short)f2bf_tr(v1[3]);
    *reinterpret_cast<short8*>(dst) = r;
  }
}

// ---------------------------------------------------------------------------
// Proj GEMM (tiled bf16, global_load_lds 1KB bursts): 128x128 tile, BK=32.
// grid: (62, 2*cb). RoPE epilogue -> qs/ks bf16 [c][head][token][64].
// ---------------------------------------------------------------------------
__global__ __launch_bounds__(256)
void k_proj_pre(const short* __restrict__ Eb, const short* __restrict__ Wb,
                const float* __restrict__ triB, const float* __restrict__ argB,
                const float* __restrict__ roleB,
                short* __restrict__ qs, short* __restrict__ ks, int b0) {
  const int nb = blockIdx.x;          // 0..61
  const int mb = blockIdx.y;
  const int n0 = nb * 128;
  const int mrow0 = b0 * LQ + mb * 128;
  const int lrow0 = mb * 128;

  const float* Bv;
  if (nb == 0)      Bv = triB;
  else if (nb == 1) Bv = argB;
  else              Bv = roleB + (n0 - 256);

  __shared__ short As[2][128 * 32];
  __shared__ short Bs[2][128 * 32];

  const int tid  = threadIdx.x;
  const int lane = tid & 63;
  const int w    = tid >> 6;
  const int wm   = (w >> 1) * 64, wn = (w & 1) * 64;
  const int l8   = lane * 8;
  const int mt0  = mrow0 >> 4;        // 16-row tile base (A)
  const int nt0  = n0 >> 4;           // 16-row tile base (B)

  f32x4 acc[4][4] = {};

  auto stage = [&](int buf, int kt) {
#pragma unroll
    for (int cc = 0; cc < 2; ++cc) {
      const int c = w * 2 + cc;        // 16-row subtile 0..7
      gload16(Eb + ((size_t)(mt0 + c) * 32 + kt) * 512 + l8, &As[buf][c * 512]);
      gload16(Wb + ((size_t)(nt0 + c) * 32 + kt) * 512 + l8, &Bs[buf][c * 512]);
    }
  };

  stage(0, 0);
  __syncthreads();
  for (int t = 0; t < 32; ++t) {
    const int buf = t & 1;
    if (t + 1 < 32) stage(buf ^ 1, t + 1);
    short8 af[4], bfr[4];
#pragma unroll
    for (int i = 0; i < 4; ++i)
      af[i] = *reinterpret_cast<const short8*>(
          &As[buf][(wm + i * 16 + (lane & 15)) * 32 + (lane >> 4) * 8]);
#pragma unroll
    for (int j = 0; j < 4; ++j)
      bfr[j] = *reinterpret_cast<const short8*>(
          &Bs[buf][(wn + j * 16 + (lane & 15)) * 32 + (lane >> 4) * 8]);
#pragma unroll
    for (int i = 0; i < 4; ++i)
#pragma unroll
      for (int j = 0; j < 4; ++j)
        acc[i][j] = __builtin_amdgcn_mfma_f32_16x16x32_bf16(af[i], bfr[j], acc[i][j], 0, 0, 0);
    __syncthreads();
  }

  // Epilogue: bias + RoPE + scatter bf16 to [c][head][token][64].
  const int col_l = lane & 15;
  const int row_h = (lane >> 4) * 4;
#pragma unroll
  for (int j = 0; j < 4; ++j) {
    const int n_loc = wn + j * 16 + col_l;
    const int gcol  = n0 + n_loc;
    const float bias = Bv[n_loc];
    const int d    = gcol & 63;
    const int head = gcol >> 7;
    const bool is_k = (gcol >> 6) & 1;
    const bool odd = d & 1;
    const float invf = rope_invf(d >> 1);
    short* dst = is_k ? ks : qs;
#pragma unroll
    for (int i = 0; i < 4; ++i) {
#pragma unroll
      for (int r = 0; r < 4; ++r) {
        float v  = acc[i][j][r] + bias;
        float vp = __shfl_xor(v, 1, 64);
        int tl  = lrow0 + wm + i * 16 + row_h + r;   // chunk-local token row
        int pos = tl & (LQ - 1);
        float s, c;
        rope_cs(pos, invf, &s, &c);
        float o = odd ? (v * c + vp * s) : (v * c - vp * s);
        dst[((size_t)(tl >> 8) * NH + head) * HSTR + (size_t)pos * 64 + d] =
            (short)f2bf(o);
      }
    }
  }
}

// ---------------------------------------------------------------------------
// Fallback proj (f32 inputs, reg-staged cvt) — same epilogue layout.
// ---------------------------------------------------------------------------
__global__ __launch_bounds__(256)
void k_proj_chunk(const float* __restrict__ E,
                  const float* __restrict__ triW, const float* __restrict__ triB,
                  const float* __restrict__ argW, const float* __restrict__ argB,
                  const float* __restrict__ roleW, const float* __restrict__ roleB,
                  short* __restrict__ qs, short* __restrict__ ks, int b0) {
  const int nb = blockIdx.x;
  const int mb = blockIdx.y;
  const int n0 = nb * 128;
  const int mrow0 = b0 * LQ + mb * 128;
  const int lrow0 = mb * 128;

  const float* W;  const float* Bv;
  if (nb == 0)      { W = triW;                             Bv = triB; }
  else if (nb == 1) { W = argW;                             Bv = argB; }
  else              { W = roleW + (size_t)(n0 - 256) * HID; Bv = roleB + (n0 - 256); }

  __shared__ short As[2][128 * 32];
  __shared__ short Bs[2][128 * 32];

  const int tid  = threadIdx.x;
  const int lane = tid & 63;
  const int w    = tid >> 6;
  const int wm   = (w >> 1) * 64, wn = (w & 1) * 64;
  const int srow = tid >> 2;
  const int scol = (tid & 3) * 8;

  f32x4 acc[4][4] = {};
  f32x4 ra0[2], ra1[2], rb0[2], rb1[2];

  auto load_regs = [&](int k0) {
    const float* pa0 = E + (size_t)(mrow0 + srow) * HID + k0 + scol;
    const float* pa1 = E + (size_t)(mrow0 + 64 + srow) * HID + k0 + scol;
    const float* pb0 = W + (size_t)(srow) * HID + k0 + scol;
    const float* pb1 = W + (size_t)(64 + srow) * HID + k0 + scol;
    ra0[0] = *reinterpret_cast<const f32x4*>(pa0);
    ra0[1] = *reinterpret_cast<const f32x4*>(pa0 + 4);
    ra1[0] = *reinterpret_cast<const f32x4*>(pa1);
    ra1[1] = *reinterpret_cast<const f32x4*>(pa1 + 4);
    rb0[0] = *reinterpret_cast<const f32x4*>(pb0);
    rb0[1] = *reinterpret_cast<const f32x4*>(pb0 + 4);
    rb1[0] = *reinterpret_cast<const f32x4*>(pb1);
    rb1[1] = *reinterpret_cast<const f32x4*>(pb1 + 4);
  };
  auto cvt8 = [&](const f32x4* v) -> short8 {
    short8 r;
    r[0] = (short)f2bf_tr(v[0][0]); r[1] = (short)f2bf_tr(v[0][1]);
    r[2] = (short)f2bf_tr(v[0][2]); r[3] = (short)f2bf_tr(v[0][3]);
    r[4] = (short)f2bf_tr(v[1][0]); r[5] = (short)f2bf_tr(v[1][1]);
    r[6] = (short)f2bf_tr(v[1][2]); r[7] = (short)f2bf_tr(v[1][3]);
    return r;
  };
  auto write_lds = [&](int buf) {
    *reinterpret_cast<short8*>(&As[buf][srow * 32 + scol])        = cvt8(ra0);
    *reinterpret_cast<short8*>(&As[buf][(64 + srow) * 32 + scol]) = cvt8(ra1);
    *reinterpret_cast<short8*>(&Bs[buf][srow * 32 + scol])        = cvt8(rb0);
    *reinterpret_cast<short8*>(&Bs[buf][(64 + srow) * 32 + scol]) = cvt8(rb1);
  };

  load_regs(0); write_lds(0); __syncthreads();
  const int NT = HID / 32;
  for (int t = 0; t < NT; ++t) {
    if (t + 1 < NT) load_regs((t + 1) * 32);
    const int buf = t & 1;
    short8 af[4], bfr[4];
#pragma unroll
    for (int i = 0; i < 4; ++i)
      af[i] = *reinterpret_cast<const short8*>(
          &As[buf][(wm + i * 16 + (lane & 15)) * 32 + (lane >> 4) * 8]);
#pragma unroll
    for (int j = 0; j < 4; ++j)
      bfr[j] = *reinterpret_cast<const short8*>(
          &Bs[buf][(wn + j * 16 + (lane & 15)) * 32 + (lane >> 4) * 8]);
#pragma unroll
    for (int i = 0; i < 4; ++i)
#pragma unroll
      for (int j = 0; j < 4; ++j)
        acc[i][j] = __builtin_amdgcn_mfma_f32_16x16x32_bf16(af[i], bfr[j], acc[i][j], 0, 0, 0);
    __syncthreads();
    if (t + 1 < NT) { write_lds((t + 1) & 1); __syncthreads(); }
  }

  const int col_l = lane & 15;
  const int row_h = (lane >> 4) * 4;
#pragma unroll
  for (int j = 0; j < 4; ++j) {
    const int n_loc = wn + j * 16 + col_l;
    const int gcol  = n0 + n_loc;
    const float bias = Bv[n_loc];
    const int d    = gcol & 63;
    const int head = gcol >> 7;
    const bool is_k = (gcol >> 6) & 1;
    const bool odd = d & 1;
    const float invf = rope_invf(d >> 1);
    short* dst = is_k ? ks : qs;
#pragma unroll
    for (int i = 0; i < 4; ++i) {
#pragma unroll
      for (int r = 0; r < 4; ++r) {
        float v  = acc[i][j][r] + bias;
        float vp = __shfl_xor(v, 1, 64);
        int tl  = lrow0 + wm + i * 16 + row_h + r;
        int pos = tl & (LQ - 1);
        float s, c;
        rope_cs(pos, invf, &s, &c);
        float o = odd ? (v * c + vp * s) : (v * c - vp * s);
        dst[((size_t)(tl >> 8) * NH + head) * HSTR + (size_t)pos * 64 + d] =
            (short)f2bf(o);
      }
    }
  }
}

// ---------------------------------------------------------------------------
// Role logits v3: 512 thr (8 waves), heads {8,8,8,8,7,7,7,7}, fixed-trip
// unrolled loops; contiguous per-head q/k frags; [16][32][60] u16 tile;
// branch-free float4 write-out. grid: (8, 16, cb)
// ---------------------------------------------------------------------------
__global__ __launch_bounds__(512)
void k_role3(const short* __restrict__ qs, const short* __restrict__ ks,
             const void* __restrict__ triu_mask, float* __restrict__ out,
             int b0) {
  const int nt = blockIdx.x, mt = blockIdx.y, bz = blockIdx.z;
  const int bg = b0 + bz;
  const int m0 = mt * 16, n0 = nt * 32;
  __shared__ uint16_t tile[16 * 32 * 60];   // 60 KB

  const int tid = threadIdx.x, lane = tid & 63, w = tid >> 6;
  const int frow = lane & 15;
  const int koff = (lane >> 4) * 8;
  const size_t cbase = (size_t)bz * NH;

  auto do_head = [&](int r) {
    const size_t hb = (cbase + 2 + r) * HSTR;
    short8 aq[2], bk[2][2];
#pragma unroll
    for (int kc = 0; kc < 2; ++kc) {
      aq[kc] = *reinterpret_cast<const short8*>(
          qs + hb + (size_t)(m0 + frow) * 64 + kc * 32 + koff);
      bk[0][kc] = *reinterpret_cast<const short8*>(
          ks + hb + (size_t)(n0 + frow) * 64 + kc * 32 + koff);
      bk[1][kc] = *reinterpret_cast<const short8*>(
          ks + hb + (size_t)(n0 + 16 + frow) * 64 + kc * 32 + koff);
    }
    f32x4 acc[2] = {};
#pragma unroll
    for (int jf = 0; jf < 2; ++jf)
#pragma unroll
      for (int kc = 0; kc < 2; ++kc)
        acc[jf] = __builtin_amdgcn_mfma_f32_16x16x32_bf16(aq[kc], bk[jf][kc], acc[jf], 0, 0, 0);
#pragma unroll
    for (int jf = 0; jf < 2; ++jf)
#pragma unroll
      for (int rg = 0; rg < 4; ++rg) {
        int m = (lane >> 4) * 4 + rg;
        int n = jf * 16 + (lane & 15);
        tile[(m * 32 + n) * 60 + r] = f2bf(acc[jf][rg]);
      }
  };

  if (w < 4) {
    const int h0 = w * 8;
#pragma unroll 2
    for (int i = 0; i < 8; ++i) do_head(h0 + i);
  } else {
    const int h0 = 32 + (w - 4) * 7;
#pragma unroll 2
    for (int i = 0; i < 7; ++i) do_head(h0 + i);
  }
  __syncthreads();

  const int mode = mask_mode(triu_mask);
  const size_t maskbase = ((size_t)bg * LQ + m0) * LQ + n0;
  const size_t outbase  = ROLE_OFF + (((size_t)bg * LQ + m0) * LQ + n0) * 60;
  for (int f = tid; f < 7680; f += 512) {         // 16*32*60/4 float4s
    int e  = f * 4;
    int m  = e / 1920;
    int x  = e - m * 1920;           // n*60 + rr, rr always <= 56
    int n_ = x / 60;
    u16x4 tv = *reinterpret_cast<const u16x4*>(&tile[e]);
    bool mk = mask_at(triu_mask, mode, maskbase + (size_t)m * LQ + n_);
    f32x4 v;
    v[0] = mk ? bf2f(tv[0]) : NEGF;
    v[1] = mk ? bf2f(tv[1]) : NEGF;
    v[2] = mk ? bf2f(tv[2]) : NEGF;
    v[3] = mk ? bf2f(tv[3]) : NEGF;
    *reinterpret_cast<f32x4*>(&out[outbase + (size_t)m * (LQ * 60) + x]) = v;
  }
}

// ---------------------------------------------------------------------------
// tri/arg logits chunk: block (mt, h, bz), 32 rows x 256. grid: (8, 2, cb)
// ---------------------------------------------------------------------------
__global__ __launch_bounds__(256)
void k_ta_chunk(const short* __restrict__ qs, const short* __restrict__ ks,
                const void* __restrict__ word_mask, float* __restrict__ out,
                int b0) {
  const int mt = blockIdx.x, h = blockIdx.y, bz = blockIdx.z;
  const int bg = b0 + bz;
  const int m0 = mt * 32;
  __shared__ uint16_t tile[32 * 256];

  const int tid = threadIdx.x, lane = tid & 63, w = tid >> 6;
  const int frow = lane & 31;
  const int koff = (lane >> 5) * 8;
  const size_t hb = ((size_t)bz * NH + h) * HSTR;

  short8 aq[4];
#pragma unroll
  for (int kc = 0; kc < 4; ++kc)
    aq[kc] = *reinterpret_cast<const short8*>(
        qs + hb + (size_t)(m0 + frow) * 64 + kc * 16 + koff);

  typedef __attribute__((ext_vector_type(16))) float f32x16l;
#pragma unroll
  for (int jn = 0; jn < 2; ++jn) {
    const int ncol0 = w * 64 + jn * 32;
    short8 bk[4];
#pragma unroll
    for (int kc = 0; kc < 4; ++kc)
      bk[kc] = *reinterpret_cast<const short8*>(
          ks + hb + (size_t)(ncol0 + frow) * 64 + kc * 16 + koff);
    f32x16l acc = {};
#pragma unroll
    for (int kc = 0; kc < 4; ++kc)
      acc = __builtin_amdgcn_mfma_f32_32x32x16_bf16(aq[kc], bk[kc], acc, 0, 0, 0);
#pragma unroll
    for (int rg = 0; rg < 16; ++rg) {
      int m = (rg & 3) + 8 * (rg >> 2) + 4 * (lane >> 5);
      int n = ncol0 + (lane & 31);
      tile[m * 256 + n] = f2bf(acc[rg]);
    }
  }
  __syncthreads();

  const int mode = mask_mode(word_mask);
  const size_t maskbase = ((size_t)bg * LQ + m0) * LQ;
  const size_t outbase  = (size_t)h * TA_OFF + ((size_t)bg * LQ + m0) * LQ;
  for (int e = tid; e < 8192; e += 256) {
    int m = e >> 8, n = e & 255;
    bool mk = mask_at(word_mask, mode, maskbase + (size_t)m * LQ + n);
    out[outbase + e] = mk ? bf2f(tile[e]) : NEGF;
  }
}

// ---------------------------------------------------------------------------
// Fallback fused tri/arg (tiny ws): LDS-resident, no scratch. grid (2,16).
// ---------------------------------------------------------------------------
__global__ __launch_bounds__(256)
void k_ta_fused(const float* __restrict__ E,
                const float* __restrict__ triW, const float* __restrict__ triB,
                const float* __restrict__ argW, const float* __restrict__ argB,
                const void* __restrict__ word_mask, float* __restrict__ out) {
  const int h = blockIdx.x, b = blockIdx.y;
  const float* W  = h ? argW : triW;
  const float* Bv = h ? argB : triB;

  __shared__ short As[2][128 * 32];
  __shared__ short Bs[2][128 * 32];
  __shared__ short qk[256 * 128];

  const int tid  = threadIdx.x;
  const int lane = tid & 63;
  const int w    = tid >> 6;
  const int wm   = (w >> 1) * 64, wn = (w & 1) * 64;
  const int srow = tid >> 2;
  const int scol = (tid & 3) * 8;
  const int col_l = lane & 15;
  const int row_h = (lane >> 4) * 4;

  for (int mi = 0; mi < 2; ++mi) {
    const int r0 = mi * 128;
    f32x4 acc[4][4] = {};
    f32x4 ra0[2], ra1[2], rb0[2], rb1[2];
    auto load_regs = [&](int k0) {
      const float* pa0 = E + ((size_t)b * LQ + r0 + srow) * HID + k0 + scol;
      const float* pa1 = E + ((size_t)b * LQ + r0 + 64 + srow) * HID + k0 + scol;
      const float* pb0 = W + (size_t)(srow) * HID + k0 + scol;
      const float* pb1 = W + (size_t)(64 + srow) * HID + k0 + scol;
      ra0[0] = *reinterpret_cast<const f32x4*>(pa0);
      ra0[1] = *reinterpret_cast<const f32x4*>(pa0 + 4);
      ra1[0] = *reinterpret_cast<const f32x4*>(pa1);
      ra1[1] = *reinterpret_cast<const f32x4*>(pa1 + 4);
      rb0[0] = *reinterpret_cast<const f32x4*>(pb0);
      rb0[1] = *reinterpret_cast<const f32x4*>(pb0 + 4);
      rb1[0] = *reinterpret_cast<const f32x4*>(pb1);
      rb1[1] = *reinterpret_cast<const f32x4*>(pb1 + 4);
    };
    auto cvt8 = [&](const f32x4* v) -> short8 {
      short8 r;
      r[0] = (short)f2bf_tr(v[0][0]); r[1] = (short)f2bf_tr(v[0][1]);
      r[2] = (short)f2bf_tr(v[0][2]); r[3] = (short)f2bf_tr(v[0][3]);
      r[4] = (short)f2bf_tr(v[1][0]); r[5] = (short)f2bf_tr(v[1][1]);
      r[6] = (short)f2bf_tr(v[1][2]); r[7] = (short)f2bf_tr(v[1][3]);
      return r;
    };
    auto write_lds = [&](int buf) {
      *reinterpret_cast<short8*>(&As[buf][srow * 32 + scol])        = cvt8(ra0);
      *reinterpret_cast<short8*>(&As[buf][(64 + srow) * 32 + scol]) = cvt8(ra1);
      *reinterpret_cast<short8*>(&Bs[buf][srow * 32 + scol])        = cvt8(rb0);
      *reinterpret_cast<short8*>(&Bs[buf][(64 + srow) * 32 + scol]) = cvt8(rb1);
    };
    load_regs(0); write_lds(0); __syncthreads();
    for (int t = 0; t < 32; ++t) {
      if (t + 1 < 32) load_regs((t + 1) * 32);
      const int buf = t & 1;
      short8 af[4], bfr[4];
#pragma unroll
      for (int i = 0; i < 4; ++i)
        af[i] = *reinterpret_cast<const short8*>(
            &As[buf][(wm + i * 16 + col_l) * 32 + (lane >> 4) * 8]);
#pragma unroll
      for (int j = 0; j < 4; ++j)
        bfr[j] = *reinterpret_cast<const short8*>(
            &Bs[buf][(wn + j * 16 + col_l) * 32 + (lane >> 4) * 8]);
#pragma unroll
      for (int i = 0; i < 4; ++i)
#pragma unroll
        for (int j = 0; j < 4; ++j)
          acc[i][j] = __builtin_amdgcn_mfma_f32_16x16x32_bf16(af[i], bfr[j], acc[i][j], 0, 0, 0);
      __syncthreads();
      if (t + 1 < 32) { write_lds((t + 1) & 1); __syncthreads(); }
    }
#pragma unroll
    for (int j = 0; j < 4; ++j) {
      const int n_loc = wn + j * 16 + col_l;
      const float bias = Bv[n_loc];
      const int d = n_loc & 63;
      const bool odd = d & 1;
      const float invf = rope_invf(d >> 1);
#pragma unroll
      for (int i = 0; i < 4; ++i) {
#pragma unroll
        for (int r = 0; r < 4; ++r) {
          float v  = acc[i][j][r] + bias;
          float vp = __shfl_xor(v, 1, 64);
          int pos = r0 + wm + i * 16 + row_h + r;
          float s, c;
          rope_cs(pos, invf, &s, &c);
          float o = odd ? (v * c + vp * s) : (v * c - vp * s);
          qk[pos * 128 + n_loc] = (short)f2bf(o);
        }
      }
    }
    __syncthreads();
  }

  const int mode = mask_mode(word_mask);
  short8 aq[4][2];
#pragma unroll
  for (int i = 0; i < 4; ++i)
#pragma unroll
    for (int kk = 0; kk < 2; ++kk)
      aq[i][kk] = *reinterpret_cast<const short8*>(
          &qk[(w * 64 + i * 16 + col_l) * 128 + kk * 32 + (lane >> 4) * 8]);

  for (int ncb = 0; ncb < 4; ++ncb) {
    const int nbase = ncb * 64;
    short8 bk[4][2];
#pragma unroll
    for (int j = 0; j < 4; ++j)
#pragma unroll
      for (int kk = 0; kk < 2; ++kk)
        bk[j][kk] = *reinterpret_cast<const short8*>(
            &qk[(nbase + j * 16 + col_l) * 128 + 64 + kk * 32 + (lane >> 4) * 8]);
    f32x4 acc[4][4] = {};
#pragma unroll
    for (int i = 0; i < 4; ++i)
#pragma unroll
      for (int j = 0; j < 4; ++j)
#pragma unroll
        for (int kk = 0; kk < 2; ++kk)
          acc[i][j] = __builtin_amdgcn_mfma_f32_16x16x32_bf16(aq[i][kk], bk[j][kk], acc[i][j], 0, 0, 0);
#pragma unroll
    for (int i = 0; i < 4; ++i)
#pragma unroll
      for (int j = 0; j < 4; ++j)
#pragma unroll
        for (int r = 0; r < 4; ++r) {
          int gm = w * 64 + i * 16 + row_h + r;
          int gn = nbase + j * 16 + col_l;
          size_t mi_ = ((size_t)b * LQ + gm) * LQ + gn;
          bool mk = mask_at(word_mask, mode, mi_);
          out[(size_t)h * TA_OFF + mi_] = mk ? acc[i][j][r] : NEGF;
        }
  }
}

// ---------------------------------------------------------------------------
extern "C" void kernel_launch(void* const* d_in, const int* in_sizes, int n_in,
                              void* d_out, int out_size, void* d_ws, size_t ws_size,
                              hipStream_t stream) {
  (void)in_sizes; (void)n_in; (void)out_size;
  const float* E     = (const float*)d_in[0];
  const float* triW  = (const float*)d_in[1];
  const float* triB  = (const float*)d_in[2];
  const float* argW  = (const float*)d_in[3];
  const float* argB  = (const float*)d_in[4];
  const float* roleW = (const float*)d_in[5];
  const float* roleB = (const float*)d_in[6];
  const void*  wmask = d_in[7];
  const void*  tmask = d_in[8];
  float* out = (float*)d_out;

  const size_t PER_B = (size_t)NH * HSTR * 2 * 2;              // 4,063,232 B
  const size_t PRE   = ((size_t)4096 * HID + (size_t)7936 * HID) * 2;  // 24.65 MB

  int cb_pre = (ws_size > PRE) ? (int)((ws_size - PRE) / PER_B) : 0;
  if (cb_pre > 16) cb_pre = 16;

  if (cb_pre >= 1) {
    short* qs = (short*)d_ws;
    short* ks = qs + (size_t)cb_pre * NH * HSTR;
    short* Eb = ks + (size_t)cb_pre * NH * HSTR;
    short* Wb = Eb + (size_t)4096 * HID;
    k_preconv<<<dim3(2048), dim3(256), 0, stream>>>(E, triW, argW, roleW, Eb, Wb);
    for (int b0 = 0; b0 < 16; b0 += cb_pre) {
      int cbi = (16 - b0 < cb_pre) ? (16 - b0) : cb_pre;
      k_proj_pre<<<dim3(62, 2 * cbi), dim3(256), 0, stream>>>(
          Eb, Wb, triB, argB, roleB, qs, ks, b0);
      k_role3<<<dim3(8, 16, cbi), dim3(512), 0, stream>>>(qs, ks, tmask, out, b0);
      k_ta_chunk<<<dim3(8, 2, cbi), dim3(256), 0, stream>>>(qs, ks, wmask, out, b0);
    }
    return;
  }

  int cb = (int)(ws_size / PER_B);
  if (cb > 16) cb = 16;
  if (cb >= 1) {
    short* qs = (short*)d_ws;
    short* ks = qs + (size_t)cb * NH * HSTR;
    for (int b0 = 0; b0 < 16; b0 += cb) {
      int cbi = (16 - b0 < cb) ? (16 - b0) : cb;
      k_proj_chunk<<<dim3(62, 2 * cbi), dim3(256), 0, stream>>>(
          E, triW, triB, argW, argB, roleW, roleB, qs, ks, b0);
      k_role3<<<dim3(8, 16, cbi), dim3(512), 0, stream>>>(qs, ks, tmask, out, b0);
      k_ta_chunk<<<dim3(8, 2, cbi), dim3(256), 0, stream>>>(qs, ks, wmask, out, b0);
    }
  } else {
    short* qs = (short*)d_out;
    short* ks = qs + (size_t)NH * HSTR;
    for (int b0 = 0; b0 < 16; ++b0) {
      k_proj_chunk<<<dim3(62, 2), dim3(256), 0, stream>>>(
          E, triW, triB, argW, argB, roleW, roleB, qs, ks, b0);
      k_role3<<<dim3(8, 16, 1), dim3(512), 0, stream>>>(qs, ks, tmask, out, b0);
    }
    k_ta_fused<<<dim3(2, 16), dim3(256), 0, stream>>>(E, triW, triB, argW, argB,
                                                      wmask, out);
  }
}